// Round 1
// baseline (127.262 us; speedup 1.0000x reference)
//
#include <hip/hip_runtime.h>
#include <hip/hip_bf16.h>

#define BN 8192
#define DIM 512
#define NB  64            // BN / 128 block-rows
#define NTILES 2080       // NB*(NB+1)/2 upper-triangle tiles
#define EPSF 1e-8f

using v8i   = __attribute__((ext_vector_type(8))) int;
using v4i   = __attribute__((ext_vector_type(4))) int;
using f32x4 = __attribute__((ext_vector_type(4))) float;

// Native exp2 (single v_exp_f32); fallback keeps exact semantics.
#if __has_builtin(__builtin_amdgcn_exp2f)
#define EXP2F(x) __builtin_amdgcn_exp2f(x)
#else
#define EXP2F(x) __expf((x) * 0.69314718055994531f)
#endif

// Async global->LDS, 16 B per lane, dest = uniform base + lane*16.
__device__ __forceinline__ void async_copy16(const void* g, void* l) {
    __builtin_amdgcn_global_load_lds(
        (const __attribute__((address_space(1))) void*)g,
        (__attribute__((address_space(3))) void*)l,
        16, 0, 0);
}

// One wave per row: L2-normalize, x4 pre-scale, fp8 e4m3; out[0] zeroed by
// block 0 (replaces a memset dispatch).
__global__ __launch_bounds__(256) void normalize_kernel(
        const float* __restrict__ emb, unsigned char* __restrict__ E,
        float* __restrict__ out) {
    if (blockIdx.x == 0 && threadIdx.x == 0) out[0] = 0.f;
    int lane = threadIdx.x & 63;
    int row  = blockIdx.x * 4 + (threadIdx.x >> 6);
    const float4* src = (const float4*)(emb + (size_t)row * DIM);
    float4 a = src[lane];
    float4 b = src[lane + 64];
    float ss = a.x*a.x + a.y*a.y + a.z*a.z + a.w*a.w
             + b.x*b.x + b.y*b.y + b.z*b.z + b.w*b.w;
    #pragma unroll
    for (int m = 1; m < 64; m <<= 1) ss += __shfl_xor(ss, m, 64);
    float s4 = 4.0f / fmaxf(sqrtf(ss), 1e-12f);
    int pa = __builtin_amdgcn_cvt_pk_fp8_f32(a.x*s4, a.y*s4, 0, false);
    pa     = __builtin_amdgcn_cvt_pk_fp8_f32(a.z*s4, a.w*s4, pa, true);
    int pb = __builtin_amdgcn_cvt_pk_fp8_f32(b.x*s4, b.y*s4, 0, false);
    pb     = __builtin_amdgcn_cvt_pk_fp8_f32(b.z*s4, b.w*s4, pb, true);
    unsigned char* rowp = E + (size_t)row * DIM;
    ((unsigned*)rowp)[lane]         = (unsigned)pa;
    ((unsigned*)(rowp + 256))[lane] = (unsigned)pb;
}

// Upper-triangle 128x128 tiles, 1D grid (2080), triangular decode.
// fp8 MX MFMA 16x16x128. A staged in LDS as 4 chunks of BK=128 (16 KB),
// DOUBLE-buffered (32 KB total, same footprint as before) with a counted
// vmcnt(8) + raw s_barrier pipeline: stage(k+1) and B-prefetch(k+1) stay
// in flight across MFMA(k); no full vmcnt(0) drain inside the K-loop.
// A-chunk XOR swizzle: LDS 16B-chunk p of row r holds global chunk p^(r&7)
// (8 chunks per 128-B row). B fragments stream global->VGPR (L2-resident,
// register double-buffered). Epilogue overlays reduction buffers on the
// A buffers; off-diag path uses neg = tot - pos (1 cndmask saved/elem) and
// a fused exp2; diag tiles handle self-exclusion separately and skip col
// sums.
__global__ __launch_bounds__(256) void gemm_epi_kernel(
        const unsigned char* __restrict__ E, const int* __restrict__ labels,
        float* __restrict__ P, float* __restrict__ N) {
    // smem: A dbuf (2 x 16 KB) overlaid with rowBuf [2][128][17]f2 (34816 B)
    // + colBuf [2][128][5]f2 (10240 B) = 45056 B.
    __shared__ __attribute__((aligned(16))) unsigned char smem[45056];
    __shared__ int labI[128];
    __shared__ int labJ[128];

    int t  = blockIdx.x;
    int bi = (int)(64.5f - sqrtf(64.5f * 64.5f - 2.0f * (float)t));
    while (64 * (bi + 1) - ((bi + 1) * bi) / 2 <= t) ++bi;
    while (64 * bi - (bi * (bi - 1)) / 2 > t) --bi;
    int bj = bi + (t - (64 * bi - (bi * (bi - 1)) / 2));
    const bool diag = (bi == bj);
    const int i0 = bi * 128;
    const int j0 = bj * 128;

    const int tid  = threadIdx.x;
    const int wave = tid >> 6;
    const int lane = tid & 63;
    const int quad = lane >> 4;
    const int lrow = lane & 15;
    const int i_w  = (wave >> 1) * 64;
    const int j_w  = (wave & 1) * 64;

    if (tid < 128)       labI[tid]       = labels[i0 + tid];
    else                 labJ[tid - 128] = labels[j0 + tid - 128];

    unsigned char* As = smem;                     // [2][128][128]
    float2* rowBuf = (float2*)smem;               // [2][128][17]
    float2* colBuf = (float2*)(smem + 34816);     // [2][128][5]
    const int vR = wave & 1;
    const int vC = wave >> 1;

    f32x4 acc[4][4];
    #pragma unroll
    for (int a = 0; a < 4; ++a)
        #pragma unroll
        for (int b = 0; b < 4; ++b)
            acc[a][b] = (f32x4){0.f, 0.f, 0.f, 0.f};

    const v4i* bptr[4];
    #pragma unroll
    for (int tj = 0; tj < 4; ++tj)
        bptr[tj] = (const v4i*)(E +
            (size_t)(j0 + j_w + tj * 16 + lrow) * DIM + quad * 32);

    v8i bf[2][4];
    #pragma unroll
    for (int tj = 0; tj < 4; ++tj) {      // prefetch B for k=0
        ((v4i*)&bf[0][tj])[0] = bptr[tj][0];
        ((v4i*)&bf[0][tj])[1] = bptr[tj][1];
    }

    // Staging lane constants: each wave covers rows [wave*32, wave*32+32),
    // 4 calls x 8 rows; lane l -> row (l>>3), LDS chunk l&7 holds global
    // chunk (l&7)^(l>>3)  (row&7 == l>>3 since bases are multiples of 8).
    const int stRow = lane >> 3;
    const int stChk = (lane & 7) ^ stRow;
    const unsigned char* gA = E + (size_t)(i0 + wave * 32 + stRow) * DIM
                                + stChk * 16;
    const int sw = lrow & 7;

    // Prologue: stage chunk 0 into buf0, full drain, barrier.
    #pragma unroll
    for (int h = 0; h < 4; ++h)
        async_copy16(gA + (size_t)h * 8 * DIM,
                     As + (size_t)(wave * 32 + h * 8) * 128);
    asm volatile("s_waitcnt vmcnt(0)" ::: "memory");
    __builtin_amdgcn_s_barrier();

    #pragma unroll
    for (int k = 0; k < 4; ++k) {
        const int cur = k & 1;
        unsigned char* bufC = As + (size_t)cur * 16384;
        if (k < 3) {                      // issue stage(k+1) -> other buffer
            unsigned char* bufN = As + (size_t)(cur ^ 1) * 16384;
            #pragma unroll
            for (int h = 0; h < 4; ++h)
                async_copy16(gA + (size_t)h * 8 * DIM + (k + 1) * 128,
                             bufN + (size_t)(wave * 32 + h * 8) * 128);
        }
        v8i af[4];
        #pragma unroll
        for (int ti = 0; ti < 4; ++ti) {
            int r = i_w + ti * 16 + lrow;
            const v4i* rp = (const v4i*)(bufC + (size_t)r * 128);
            ((v4i*)&af[ti])[0] = rp[(quad * 2) ^ sw];
            ((v4i*)&af[ti])[1] = rp[(quad * 2 + 1) ^ sw];
        }
        if (k < 3) {                      // prefetch next k's B
            #pragma unroll
            for (int tj = 0; tj < 4; ++tj) {
                ((v4i*)&bf[cur ^ 1][tj])[0] = bptr[tj][(k + 1) * 8];
                ((v4i*)&bf[cur ^ 1][tj])[1] = bptr[tj][(k + 1) * 8 + 1];
            }
        }
        #pragma unroll
        for (int ti = 0; ti < 4; ++ti)
            #pragma unroll
            for (int tj = 0; tj < 4; ++tj)
                acc[ti][tj] =
                    __builtin_amdgcn_mfma_scale_f32_16x16x128_f8f6f4(
                        af[ti], bf[cur][tj], acc[ti][tj],
                        0, 0,                 // fp8 e4m3 / e4m3
                        0, 0x7F7F7F7F,        // A scale = 1.0
                        0, 0x7F7F7F7F);       // B scale = 1.0
        if (k < 3) {
            // Retire only the 4 stage(k+1) loads (oldest); leave the 8
            // B(k+1) prefetch loads in flight across the barrier.
            asm volatile("s_waitcnt vmcnt(8)" ::: "memory");
            __builtin_amdgcn_s_barrier();
        }
    }
    __syncthreads();      // As dead -> reduction buffers writable

    // Epilogue. C/D: col = lane&15, row = quad*4 + reg. acc = 16*S.
    // w = exp(S-1) = exp2(acc * log2e/16 - log2e).
    const float K1 = 0.0901619783824569f;    // log2(e)/16
    const float K2 = -1.4426950408889634f;   // -log2(e)
    if (!diag) {
        float psC[4] = {0.f, 0.f, 0.f, 0.f};
        float tsC[4] = {0.f, 0.f, 0.f, 0.f};
        #pragma unroll
        for (int ti = 0; ti < 4; ++ti) {
            #pragma unroll
            for (int reg = 0; reg < 4; ++reg) {
                int irow = i_w + ti * 16 + quad * 4 + reg;
                int li   = labI[irow];
                float ps = 0.f, ts = 0.f;
                #pragma unroll
                for (int tj = 0; tj < 4; ++tj) {
                    int jcol = j_w + tj * 16 + lrow;
                    float w  = EXP2F(fmaf(acc[ti][tj][reg], K1, K2));
                    float wp = (li == labJ[jcol]) ? w : 0.f;
                    ps += wp;  ts += w;
                    psC[tj] += wp;  tsC[tj] += w;
                }
                rowBuf[(size_t)(vR * 128 + irow) * 17 + lrow] =
                    (float2){ps, ts - ps};
            }
        }
        #pragma unroll
        for (int tj = 0; tj < 4; ++tj) {
            int jcol = j_w + tj * 16 + lrow;
            colBuf[(size_t)(vC * 128 + jcol) * 5 + quad] =
                (float2){psC[tj], tsC[tj] - psC[tj]};
        }
    } else {
        // Diag tile: self pair (irow == jcol) excluded from pos exactly;
        // col sums unused (row path covers the full square).
        #pragma unroll
        for (int ti = 0; ti < 4; ++ti) {
            #pragma unroll
            for (int reg = 0; reg < 4; ++reg) {
                int irow = i_w + ti * 16 + quad * 4 + reg;
                int li   = labI[irow];
                float ps = 0.f, ts = 0.f, sf = 0.f;
                #pragma unroll
                for (int tj = 0; tj < 4; ++tj) {
                    int jcol = j_w + tj * 16 + lrow;
                    float w  = EXP2F(fmaf(acc[ti][tj][reg], K1, K2));
                    float wp = (li == labJ[jcol]) ? w : 0.f;
                    float wd = (irow == jcol) ? w : 0.f;
                    ps += wp;  ts += w;  sf += wd;
                }
                rowBuf[(size_t)(vR * 128 + irow) * 17 + lrow] =
                    (float2){ps - sf, ts - ps};
            }
        }
    }
    __syncthreads();

    if (tid < 128) {
        const float2* a = rowBuf + (size_t)tid * 17;
        const float2* b = rowBuf + (size_t)(128 + tid) * 17;
        float sp = 0.f, sn = 0.f;
        #pragma unroll
        for (int u = 0; u < 16; ++u) {
            sp += a[u].x + b[u].x;
            sn += a[u].y + b[u].y;
        }
        P[(size_t)bj * BN + i0 + tid] = sp;
        N[(size_t)bj * BN + i0 + tid] = sn;
    } else if (!diag) {
        int c2 = tid - 128;
        const float2* a = colBuf + (size_t)c2 * 5;
        const float2* b = colBuf + (size_t)(128 + c2) * 5;
        float sp = 0.f, sn = 0.f;
        #pragma unroll
        for (int u = 0; u < 4; ++u) {
            sp += a[u].x + b[u].x;
            sn += a[u].y + b[u].y;
        }
        P[(size_t)bi * BN + j0 + c2] = sp;
        N[(size_t)bi * BN + j0 + c2] = sn;
    }
}

// Fused tail: 32 blocks x 256. Per-block LDS histogram, per-row partial
// reduce + loss, one atomicAdd of the pre-scaled block sum into out[0].
__global__ __launch_bounds__(256) void reduce_finalize_kernel(
        const int* __restrict__ labels, const float* __restrict__ P,
        const float* __restrict__ N, float* __restrict__ out) {
    __shared__ int cnt[128];
    __shared__ float wsum[4];
    int tid = threadIdx.x;
    if (tid < 128) cnt[tid] = 0;
    __syncthreads();
    for (int i = tid; i < BN; i += 256) atomicAdd(&cnt[labels[i]], 1);
    __syncthreads();

    int i = blockIdx.x * 256 + tid;
    float p = 0.f, n = 0.f;
    #pragma unroll 8
    for (int c = 0; c < NB; ++c) {
        p += P[(size_t)c * BN + i];
        n += N[(size_t)c * BN + i];
    }
    int   cl = cnt[labels[i]];
    float pm = p / fmaxf((float)(cl - 1), 1.0f);
    float nm = n / fmaxf((float)(BN - cl), 1.0f);
    float v  = ((cl - 1 > 0) && (BN - cl > 0))
                   ? -logf(pm / (pm + nm + EPSF)) : 0.0f;
    v *= (1.0f / (float)BN);
    #pragma unroll
    for (int m = 1; m < 64; m <<= 1) v += __shfl_xor(v, m, 64);
    if ((tid & 63) == 0) wsum[tid >> 6] = v;
    __syncthreads();
    if (tid == 0)
        atomicAdd(out, wsum[0] + wsum[1] + wsum[2] + wsum[3]);
}

extern "C" void kernel_launch(void* const* d_in, const int* in_sizes, int n_in,
                              void* d_out, int out_size, void* d_ws, size_t ws_size,
                              hipStream_t stream) {
    const float* emb   = (const float*)d_in[0];
    const int* labels  = (const int*)d_in[1];
    float* out         = (float*)d_out;

    // ws layout: E (8 MB reserved; fp8 uses 4) | P (2 MB) | N (2 MB)
    unsigned char* E   = (unsigned char*)d_ws;
    float* P           = (float*)((char*)d_ws + (size_t)BN * DIM * 2);
    float* N           = P + (size_t)NB * BN;

    normalize_kernel<<<BN / 4, 256, 0, stream>>>(emb, E, out);
    gemm_epi_kernel<<<NTILES, 256, 0, stream>>>(E, labels, P, N);
    reduce_finalize_kernel<<<32, 256, 0, stream>>>(labels, P, N, out);
}